// Round 8
// baseline (3750.164 us; speedup 1.0000x reference)
//
#include <hip/hip_runtime.h>

// BaseRNN B=64,S=512,H=E=512,L=2 — persistent kernel, R18.
// R15/16/17 established: protocol/venue/ring tweaks all <=1% (2918/2952/2936).
// Phase = 5.7us, compute 0.85us, rest = serial sync chain. R18 attacks chain
// POSITION, not hop cost: split the GEMV into A-half (input available at
// phase start: l0=prefetched emb, l1=h0[p] from the leading layer) and
// B-half (self-chain h[p-1] from own-layer peers, straggler-bound flag).
// New phase: stage Xa -> va compute (reduced to 1 reg/group) -> DEFERRED
// self-flag poll -> stage Xb -> vb + combine -> finalize/store/publish.
// The self-chain wait is hidden under ~0.6-0.7us of A-half work.
// Polls are per-wave replicated (each wave gates itself) -> exchange barrier
// dropped; still 3 barriers/phase. R17's G/sc0 flags reverted (flat).
// Extra cost: one extra RSTEP chain per group (~60 shfl) + 4 VGPRs.

#define BATCH 64
#define SEQ   512
#define HID   512
#define NTHR  256
#define CB    8
#define ROWS  32
#define SLOT  (BATCH * HID)     // floats per ring slot (128KB)
#define RING  8

typedef unsigned int u32;

__device__ __forceinline__ float dot4(const float4 a, const float4 b) {
  return a.x * b.x + a.y * b.y + a.z * b.z + a.w * b.w;
}
__device__ __forceinline__ float2 ld2(const double* p) {   // sc1 8B load
  const double d = __hip_atomic_load(p, __ATOMIC_RELAXED, __HIP_MEMORY_SCOPE_AGENT);
  return __builtin_bit_cast(float2, d);
}
__device__ __forceinline__ void st2(double* p, float2 v) { // sc1 8B store
  __hip_atomic_store(p, __builtin_bit_cast(double, v),
                     __ATOMIC_RELAXED, __HIP_MEMORY_SCOPE_AGENT);
}
__device__ __forceinline__ u32 ldf(const u32* p) {         // sc1 flag load
  return __hip_atomic_load(p, __ATOMIC_RELAXED, __HIP_MEMORY_SCOPE_AGENT);
}
__device__ __forceinline__ float tanh_fast(float x) {
  const float a = fabsf(x);
  const float e = __expf(-2.0f * a);
  const float t = (1.0f - e) * __builtin_amdgcn_rcpf(1.0f + e);
  return copysignf(t, x);
}
#define WAIT_VM0() asm volatile("s_waitcnt vmcnt(0)" ::: "memory")

#define RSTEP(D, N)                                                   \
  {                                                                   \
    const bool hi = (lane & (D)) != 0;                                \
    _Pragma("unroll")                                                 \
    for (int a = 0; a < (N); ++a) {                                   \
      const float keep = hi ? v[a + (N)] : v[a];                      \
      const float send = hi ? v[a] : v[a + (N)];                      \
      v[a] = keep + __shfl_xor(send, (D));                            \
    }                                                                 \
  }

__global__ __launch_bounds__(NTHR, 1) void rnn_persistent(
    const int* __restrict__ x, const int* __restrict__ lengths,
    const float* __restrict__ emb,
    const float* __restrict__ W_ih, const float* __restrict__ W_hh,
    const float* __restrict__ b_ih, const float* __restrict__ b_hh,
    float* __restrict__ out,
    float* h0r, float* h1r, u32* F, int ring)
{
  __shared__ __align__(16) float Xa[CB][HID];        // 16KB
  __shared__ __align__(16) float Xb[CB][HID];        // 16KB
  __shared__ __align__(16) float Xpart[CB][ROWS][4]; // 4KB
  __shared__ int Lens[CB];

  const int wg    = blockIdx.x;
  const int tid   = threadIdx.x;
  const int dom   = wg & 7;
  const int q     = wg >> 3;
  const int layer = q >> 4;
  const int rg    = q & 15;
  const int bbase = dom * CB;
  const int jbase = rg * ROWS;
  const int tj    = tid >> 6;
  const int lane  = tid & 63;

  // flags: entry (dom,layer,rg) on its own 128B line; value = #slots written
  u32* Fown = F + ((dom * 2 + layer) * 16 + rg) * 32;
  u32* F0   = F + ((dom * 2 + 0) * 16) * 32;   // + i*32
  u32* F1   = F + ((dom * 2 + 1) * 16) * 32;

  // ---- weights in registers: 8 j x (2 float4 k) x 2 mats = 128 VGPRs ----
  float4 wa[2][8], wb[2][8];
  {
    const float* WA = W_ih + layer * (HID * HID);
    const float* WB = W_hh + layer * (HID * HID);
    #pragma unroll
    for (int ji = 0; ji < 8; ++ji) {
      const int j = jbase + tj * 8 + ji;
      #pragma unroll
      for (int i = 0; i < 2; ++i) {
        const int k = i * 256 + 4 * lane;
        wa[i][ji] = *(const float4*)&WA[j * HID + k];
        wb[i][ji] = *(const float4*)&WB[j * HID + k];
      }
    }
  }
  if (tid < CB) Lens[tid] = lengths[bbase + tid];
  __syncthreads();
  int maxlen = Lens[0];
  #pragma unroll
  for (int i = 1; i < CB; ++i) maxlen = max(maxlen, Lens[i]);
  const int P     = maxlen;                       // 1..512
  const int pl0   = (P < SEQ) ? P : (SEQ - 1);    // l0's last active phase
  const int plast = layer ? P : pl0;
  int lm[4];                                      // group liveness bounds
  #pragma unroll
  for (int g = 0; g < 4; ++g) lm[g] = max(Lens[2 * g], Lens[2 * g + 1]);

  float4 bias4 = make_float4(0.f, 0.f, 0.f, 0.f);
  if (tid < 64) {
    const int jq = jbase + (tid & 7) * 4;
    bias4.x = b_ih[layer * HID + jq + 0] + b_hh[layer * HID + jq + 0];
    bias4.y = b_ih[layer * HID + jq + 1] + b_hh[layer * HID + jq + 1];
    bias4.z = b_ih[layer * HID + jq + 2] + b_hh[layer * HID + jq + 2];
    bias4.w = b_ih[layer * HID + jq + 3] + b_hh[layer * HID + jq + 3];
  }

  // ---- initial emb prefetch (t=0, l0) ----
  float4 pf[4];
  if (layer == 0) {
    #pragma unroll
    for (int i = 0; i < 4; ++i) {
      const int u = tid + NTHR * i;
      const int r = u >> 7, c = (u & 127) * 4;
      const int tok = x[(bbase + r) * SEQ];
      pf[i] = *(const float4*)&emb[(size_t)tok * HID + c];
    }
  }

  int cur = 0, prev = ring - 1;   // p % ring, (p-1) % ring

  for (int p = 0; p <= P; ++p) {
    const bool active = layer ? (p >= 1) : (p < SEQ);
    const int  wr0    = (cur + 1 == ring) ? 0 : (cur + 1);

    if (active) {
      const int t = layer ? (p - 1) : p;

      // ---- A-gate (l1 only, per-wave): h0[cur] needs F0 >= p; l0 leads a
      // phase so this is usually already satisfied ----
      if (layer) {
        const u32* fp = F0 + (lane & 15) * 32;
        bool ok = (lane >= 16);
        while (true) {
          if (!ok) ok = (ldf(fp) >= (u32)p);
          if (__ballot(ok) == ~0ull) break;
          __builtin_amdgcn_s_sleep(1);
        }
      }

      // ---- A-stage: Xa <- (l0: prefetched emb) / (l1: h0[cur]) ----
      if (layer == 0) {
        #pragma unroll
        for (int i = 0; i < 4; ++i) {
          const int u = tid + NTHR * i;
          *(float4*)&Xa[u >> 7][(u & 127) * 4] = pf[i];
        }
      } else {
        const double* srcA = (const double*)(h0r) + (size_t)cur * (SLOT / 2);
        float2 ta[8];
        #pragma unroll
        for (int i = 0; i < 8; ++i) {
          const int u = tid + NTHR * i;
          ta[i] = ld2(&srcA[(size_t)(bbase + (u >> 8)) * 256 + (u & 255)]);
        }
        #pragma unroll
        for (int i = 0; i < 8; ++i) {
          const int u = tid + NTHR * i;
          *(float2*)&Xa[u >> 8][(u & 255) * 2] = ta[i];
        }
      }
      __syncthreads();   // bar 1

      // ---- A-half compute: va per group, fully reduced to 1 reg/group ----
      float va1[4];
      #pragma unroll
      for (int g = 0; g < 4; ++g) {
        va1[g] = 0.f;
        if (t >= lm[g]) continue;            // wave-uniform (Lens shared)
        float v[16];
        #pragma unroll
        for (int o = 0; o < 16; ++o) v[o] = 0.f;
        #pragma unroll
        for (int bi = 0; bi < 2; ++bi) {
          const int b = g * 2 + bi;
          const float4 xa0 = *(const float4*)&Xa[b][4 * lane];
          const float4 xa1 = *(const float4*)&Xa[b][256 + 4 * lane];
          #pragma unroll
          for (int ji = 0; ji < 8; ++ji) {
            v[bi * 8 + ji] += dot4(wa[0][ji], xa0) + dot4(wa[1][ji], xa1);
          }
        }
        RSTEP(32, 8)
        RSTEP(16, 4)
        RSTEP(8, 2)
        RSTEP(4, 1)
        va1[g] = v[0];
      }

      // ---- DEFERRED self-chain poll (per-wave): l0: F0>=p (+WAR throttle
      // F1 >= p+1-ring before storing slot p+1); l1: F1 >= p-1 ----
      {
        const u32* fp = Fown;
        u32 tgt = 0;
        bool ok = true;
        if (lane < 16) {
          fp = (layer ? F1 : F0) + lane * 32;
          tgt = layer ? (u32)(p - 1) : (u32)p;
          ok = false;
        } else if (lane < 32 && layer == 0) {
          const int th = p + 1 - ring;
          if (th > 0) { fp = F1 + (lane - 16) * 32; tgt = (u32)th; ok = false; }
        }
        while (true) {
          if (!ok) ok = (ldf(fp) >= tgt);
          if (__ballot(ok) == ~0ull) break;
          __builtin_amdgcn_s_sleep(1);
        }
      }

      // ---- B-stage: Xb <- (l0: h0[cur]) / (l1: h1[prev]) ----
      {
        const double* srcB = layer
            ? (const double*)(h1r) + (size_t)prev * (SLOT / 2)
            : (const double*)(h0r) + (size_t)cur  * (SLOT / 2);
        float2 tb[8];
        #pragma unroll
        for (int i = 0; i < 8; ++i) {
          const int u = tid + NTHR * i;
          tb[i] = ld2(&srcB[(size_t)(bbase + (u >> 8)) * 256 + (u & 255)]);
        }
        #pragma unroll
        for (int i = 0; i < 8; ++i) {
          const int u = tid + NTHR * i;
          *(float2*)&Xb[u >> 8][(u & 255) * 2] = tb[i];
        }
      }
      __syncthreads();   // bar 2

      // ---- B-half compute + combine + reduce ----
      #pragma unroll 2
      for (int g = 0; g < 4; ++g) {
        if (t >= lm[g]) continue;
        float v[16];
        #pragma unroll
        for (int o = 0; o < 16; ++o) v[o] = 0.f;
        #pragma unroll
        for (int bi = 0; bi < 2; ++bi) {
          const int b = g * 2 + bi;
          const float4 xb0 = *(const float4*)&Xb[b][4 * lane];
          const float4 xb1 = *(const float4*)&Xb[b][256 + 4 * lane];
          #pragma unroll
          for (int ji = 0; ji < 8; ++ji) {
            v[bi * 8 + ji] += dot4(wb[0][ji], xb0) + dot4(wb[1][ji], xb1);
          }
        }
        RSTEP(32, 8)
        RSTEP(16, 4)
        RSTEP(8, 2)
        RSTEP(4, 1)
        const int b_o = g * 2 + (lane >> 5);
        const int j_o = tj * 8 + ((lane >> 2) & 7);
        Xpart[b_o][j_o][lane & 3] = v[0] + va1[g];
      }
      __syncthreads();   // bar 3

      // ---- finalize: sum partials, fast tanh, mask, sc1 ring store ----
      if (tid < 64) {
        const int b = tid >> 3, jq = (tid & 7) * 4;
        const float4 hb = *(const float4*)&Xb[b][jbase + jq];
        const bool live = (t < Lens[b]);
        float4 r = hb;
        if (live) {
          const float4 p0 = *(const float4*)&Xpart[b][jq + 0][0];
          const float4 p1 = *(const float4*)&Xpart[b][jq + 1][0];
          const float4 p2 = *(const float4*)&Xpart[b][jq + 2][0];
          const float4 p3 = *(const float4*)&Xpart[b][jq + 3][0];
          r.x = tanh_fast(p0.x + p0.y + p0.z + p0.w + bias4.x);
          r.y = tanh_fast(p1.x + p1.y + p1.z + p1.w + bias4.y);
          r.z = tanh_fast(p2.x + p2.y + p2.z + p2.w + bias4.z);
          r.w = tanh_fast(p3.x + p3.y + p3.z + p3.w + bias4.w);
        }
        double* dst = layer ? ((double*)h1r + (size_t)cur * (SLOT / 2))
                            : ((double*)h0r + (size_t)wr0 * (SLOT / 2));
        const size_t di = (size_t)(bbase + b) * 256 + ((jbase + jq) >> 1);
        st2(&dst[di],     make_float2(r.x, r.y));
        st2(&dst[di + 1], make_float2(r.z, r.w));
        if (p == plast) {   // fused epilogue: own tile = own output
          if (layer == 0) {
            *(float4*)&out[32768 + (size_t)(bbase + b) * 1024 + jbase + jq] = r;
          } else {
            *(float4*)&out[(size_t)(bbase + b) * 512 + jbase + jq] = r;
            *(float4*)&out[32768 + (size_t)(bbase + b) * 1024 + 512 + jbase + jq] = r;
          }
        }
        // drain own ring stores, then publish (wave0-local: ring data is
        // written and drained exclusively by wave 0)
        WAIT_VM0();
        if (tid == 0)
          __hip_atomic_store(Fown, (u32)(layer ? p : (p + 1)),
                             __ATOMIC_RELAXED, __HIP_MEMORY_SCOPE_AGENT);
      }
    }

    // ---- exchange tail: l0 emb prefetch for next phase (no barrier; the
    // next phase's bar-1 orders everything; polls are per-wave) ----
    const int np = p + 1;
    if (layer == 0 && np <= plast) {
      #pragma unroll
      for (int i = 0; i < 4; ++i) {
        const int u = tid + NTHR * i;
        const int r = u >> 7, c = (u & 127) * 4;
        const int tok = x[(bbase + r) * SEQ + np];
        pf[i] = *(const float4*)&emb[(size_t)tok * HID + c];
      }
    }
    prev = cur; cur = wr0;
  }
}

extern "C" void kernel_launch(void* const* d_in, const int* in_sizes, int n_in,
                              void* d_out, int out_size, void* d_ws, size_t ws_size,
                              hipStream_t stream) {
  (void)in_sizes; (void)n_in; (void)out_size; (void)ws_size;
  const int*   x       = (const int*)d_in[0];
  const int*   lengths = (const int*)d_in[1];
  const float* emb     = (const float*)d_in[2];
  const float* W_ih    = (const float*)d_in[3];
  const float* W_hh    = (const float*)d_in[4];
  const float* b_ih    = (const float*)d_in[5];
  const float* b_hh    = (const float*)d_in[6];
  float* out = (float*)d_out;

  const size_t slotB = (size_t)SLOT * sizeof(float);   // 128KB
  const int ring = RING;                               // 8

  float* h0r = (float*)d_ws;
  float* h1r = h0r + (size_t)ring * SLOT;
  u32*   F   = (u32*)(h1r + (size_t)ring * SLOT);

  // zero slot 0 of each ring (h(-1)=0) + flag page; ws re-poisoned each call
  hipMemsetAsync(h0r, 0, slotB, stream);
  hipMemsetAsync(h1r, 0, slotB, stream);
  hipMemsetAsync(F, 0, 32768, stream);

  hipLaunchKernelGGL(rnn_persistent, dim3(256), dim3(NTHR), 0, stream,
                     x, lengths, emb, W_ih, W_hh, b_ih, b_hh, out,
                     h0r, h1r, F, ring);
}

// Round 9
// 3650.490 us; speedup vs baseline: 1.0273x; 1.0273x over previous
//
#include <hip/hip_runtime.h>

// BaseRNN B=64,S=512,H=E=512,L=2 — persistent kernel, R19.
// Ledger: R15 best=2918 (R10 protocol + latched poll/sleep/early-publish).
// Flat/regressed: hop-count (R11), sc0 venue (R14/R17), ring size (R16),
// intra-phase A/B overlap (R18: serialized stages + regalloc 112->108).
// R19 tests the ONE untested term: SYNC DEGREE. 8 WGs x 512 thr per
// (dom,layer) instead of 16 x 256. Ballot waits max-of-8 publishes (was 16),
// poll fans in over 8 flag lines, grid 256->128 WGs, stage 4 loads/thread
// (was 8). Per-thread shape preserved EXACTLY (8 rows/tj-group, wa[2][8],
// same v[16] loop/RSTEP) so regalloc is undisturbed; 512 thr = 8 waves/CU
// allows 256 VGPR -> no occupancy cliff. Finalize stays wave0-only (2 tiles
// per thread) so early-publish-after-own-drain stays sound.
// H6 real -> ~2.65-2.85ms; flat -> serial chain is the floor (roofline).

#define BATCH 64
#define SEQ   512
#define HID   512
#define NTHR  512
#define CB    8
#define ROWS  64
#define NWG   8                 // WGs per (dom,layer)
#define SLOT  (BATCH * HID)     // floats per ring slot (128KB)
#define RING  8

typedef unsigned int u32;

__device__ __forceinline__ float dot4(const float4 a, const float4 b) {
  return a.x * b.x + a.y * b.y + a.z * b.z + a.w * b.w;
}
__device__ __forceinline__ float2 ld2(const double* p) {   // sc1 8B load
  const double d = __hip_atomic_load(p, __ATOMIC_RELAXED, __HIP_MEMORY_SCOPE_AGENT);
  return __builtin_bit_cast(float2, d);
}
__device__ __forceinline__ void st2(double* p, float2 v) { // sc1 8B store
  __hip_atomic_store(p, __builtin_bit_cast(double, v),
                     __ATOMIC_RELAXED, __HIP_MEMORY_SCOPE_AGENT);
}
__device__ __forceinline__ u32 ldf(const u32* p) {         // sc1 flag load
  return __hip_atomic_load(p, __ATOMIC_RELAXED, __HIP_MEMORY_SCOPE_AGENT);
}
__device__ __forceinline__ float tanh_fast(float x) {
  const float a = fabsf(x);
  const float e = __expf(-2.0f * a);
  const float t = (1.0f - e) * __builtin_amdgcn_rcpf(1.0f + e);
  return copysignf(t, x);
}
#define WAIT_VM0() asm volatile("s_waitcnt vmcnt(0)" ::: "memory")

#define RSTEP(D, N)                                                   \
  {                                                                   \
    const bool hi = (lane & (D)) != 0;                                \
    _Pragma("unroll")                                                 \
    for (int a = 0; a < (N); ++a) {                                   \
      const float keep = hi ? v[a + (N)] : v[a];                      \
      const float send = hi ? v[a] : v[a + (N)];                      \
      v[a] = keep + __shfl_xor(send, (D));                            \
    }                                                                 \
  }

__global__ __launch_bounds__(NTHR, 1) void rnn_persistent(
    const int* __restrict__ x, const int* __restrict__ lengths,
    const float* __restrict__ emb,
    const float* __restrict__ W_ih, const float* __restrict__ W_hh,
    const float* __restrict__ b_ih, const float* __restrict__ b_hh,
    float* __restrict__ out,
    float* h0r, float* h1r, u32* F, int ring)
{
  __shared__ __align__(16) float Xa[CB][HID];        // 16KB
  __shared__ __align__(16) float Xb[CB][HID];        // 16KB
  __shared__ __align__(16) float Xpart[CB][ROWS][4]; // 8KB
  __shared__ int Lens[CB];

  const int wg    = blockIdx.x;
  const int tid   = threadIdx.x;
  const int dom   = wg & 7;
  const int q     = wg >> 3;
  const int layer = q >> 3;
  const int rg    = q & 7;
  const int bbase = dom * CB;
  const int jbase = rg * ROWS;
  const int tj    = tid >> 6;    // 0..7
  const int lane  = tid & 63;

  // flags: entry (dom,layer,rg) on its own 128B line; value = #slots written
  u32* Fown = F + ((dom * 2 + layer) * NWG + rg) * 32;
  u32* F0   = F + ((dom * 2 + 0) * NWG) * 32;   // + i*32
  u32* F1   = F + ((dom * 2 + 1) * NWG) * 32;

  // ---- weights in registers: 8 j x (2 float4 k) x 2 mats = 128 VGPRs ----
  float4 wa[2][8], wb[2][8];
  {
    const float* WA = W_ih + layer * (HID * HID);
    const float* WB = W_hh + layer * (HID * HID);
    #pragma unroll
    for (int ji = 0; ji < 8; ++ji) {
      const int j = jbase + tj * 8 + ji;
      #pragma unroll
      for (int i = 0; i < 2; ++i) {
        const int k = i * 256 + 4 * lane;
        wa[i][ji] = *(const float4*)&WA[j * HID + k];
        wb[i][ji] = *(const float4*)&WB[j * HID + k];
      }
    }
  }
  if (tid < CB) Lens[tid] = lengths[bbase + tid];
  __syncthreads();
  int maxlen = Lens[0];
  #pragma unroll
  for (int i = 1; i < CB; ++i) maxlen = max(maxlen, Lens[i]);
  const int P     = maxlen;                       // 1..512
  const int pl0   = (P < SEQ) ? P : (SEQ - 1);    // l0's last active phase
  const int plast = layer ? P : pl0;
  int lm[4];                                      // group liveness bounds
  #pragma unroll
  for (int g = 0; g < 4; ++g) lm[g] = max(Lens[2 * g], Lens[2 * g + 1]);

  // bias for finalize (wave0 handles 2 output tiles/thread: idx = tid, tid+64)
  float4 bias4[2] = {make_float4(0.f, 0.f, 0.f, 0.f),
                     make_float4(0.f, 0.f, 0.f, 0.f)};
  if (tid < 64) {
    #pragma unroll
    for (int k = 0; k < 2; ++k) {
      const int idx = tid + 64 * k;
      const int jq = jbase + (idx & 15) * 4;
      bias4[k].x = b_ih[layer * HID + jq + 0] + b_hh[layer * HID + jq + 0];
      bias4[k].y = b_ih[layer * HID + jq + 1] + b_hh[layer * HID + jq + 1];
      bias4[k].z = b_ih[layer * HID + jq + 2] + b_hh[layer * HID + jq + 2];
      bias4[k].w = b_ih[layer * HID + jq + 3] + b_hh[layer * HID + jq + 3];
    }
  }

  // ---- initial emb prefetch (t=0, l0): 1024 float4 over 512 threads ----
  float4 pf[2];
  if (layer == 0) {
    #pragma unroll
    for (int i = 0; i < 2; ++i) {
      const int u = tid + NTHR * i;
      const int r = u >> 7, c = (u & 127) * 4;
      const int tok = x[(bbase + r) * SEQ];
      pf[i] = *(const float4*)&emb[(size_t)tok * HID + c];
    }
  }

  int cur = 0, prev = ring - 1;   // p % ring, (p-1) % ring

  for (int p = 0; p <= P; ++p) {
    const bool active = layer ? (p >= 1) : (p < SEQ);
    const int  wr0    = (cur + 1 == ring) ? 0 : (cur + 1);

    if (active) {
      const int t = layer ? (p - 1) : p;

      // ---- stage: sc1 ring loads -> LDS (4 x 8B per thread) ----
      if (layer == 0) {
        const double* src = (const double*)(h0r) + (size_t)cur * (SLOT / 2);
        float2 tv[4];
        #pragma unroll
        for (int i = 0; i < 4; ++i) {
          const int u = tid + NTHR * i;
          tv[i] = ld2(&src[(size_t)(bbase + (u >> 8)) * 256 + (u & 255)]);
        }
        #pragma unroll
        for (int i = 0; i < 4; ++i) {
          const int u = tid + NTHR * i;
          *(float2*)&Xb[u >> 8][(u & 255) * 2] = tv[i];
        }
        #pragma unroll
        for (int i = 0; i < 2; ++i) {
          const int u = tid + NTHR * i;
          *(float4*)&Xa[u >> 7][(u & 127) * 4] = pf[i];
        }
      } else {
        const double* srcB = (const double*)(h1r) + (size_t)prev * (SLOT / 2);
        const double* srcA = (const double*)(h0r) + (size_t)cur  * (SLOT / 2);
        float2 tb[4], ta[4];
        #pragma unroll
        for (int i = 0; i < 4; ++i) {
          const int u = tid + NTHR * i;
          tb[i] = ld2(&srcB[(size_t)(bbase + (u >> 8)) * 256 + (u & 255)]);
        }
        #pragma unroll
        for (int i = 0; i < 4; ++i) {
          const int u = tid + NTHR * i;
          ta[i] = ld2(&srcA[(size_t)(bbase + (u >> 8)) * 256 + (u & 255)]);
        }
        #pragma unroll
        for (int i = 0; i < 4; ++i) {
          const int u = tid + NTHR * i;
          *(float2*)&Xb[u >> 8][(u & 255) * 2] = tb[i];
          *(float2*)&Xa[u >> 8][(u & 255) * 2] = ta[i];
        }
      }
      __syncthreads();

      // ---- compute: 4 groups, unroll 2; skip fully-frozen groups ----
      #pragma unroll 2
      for (int g = 0; g < 4; ++g) {
        if (t >= lm[g]) continue;            // wave-uniform (Lens shared)
        float v[16];
        #pragma unroll
        for (int o = 0; o < 16; ++o) v[o] = 0.f;
        #pragma unroll
        for (int bi = 0; bi < 2; ++bi) {
          const int b = g * 2 + bi;
          const float4 xa0 = *(const float4*)&Xa[b][4 * lane];
          const float4 xa1 = *(const float4*)&Xa[b][256 + 4 * lane];
          const float4 xb0 = *(const float4*)&Xb[b][4 * lane];
          const float4 xb1 = *(const float4*)&Xb[b][256 + 4 * lane];
          #pragma unroll
          for (int ji = 0; ji < 8; ++ji) {
            v[bi * 8 + ji] += dot4(wa[0][ji], xa0) + dot4(wa[1][ji], xa1)
                            + dot4(wb[0][ji], xb0) + dot4(wb[1][ji], xb1);
          }
        }
        RSTEP(32, 8)
        RSTEP(16, 4)
        RSTEP(8, 2)
        RSTEP(4, 1)
        const int b_o = g * 2 + (lane >> 5);
        const int j_o = tj * 8 + ((lane >> 2) & 7);
        Xpart[b_o][j_o][lane & 3] = v[0];
      }
      __syncthreads();

      // ---- finalize (wave0 only, 2 tiles/thread): tanh, mask, ring store ----
      if (tid < 64) {
        #pragma unroll
        for (int k = 0; k < 2; ++k) {
          const int idx = tid + 64 * k;
          const int b = idx >> 4, jq = (idx & 15) * 4;
          const float4 hb = *(const float4*)&Xb[b][jbase + jq];
          const bool live = (t < Lens[b]);
          float4 r = hb;
          if (live) {
            const float4 p0 = *(const float4*)&Xpart[b][jq + 0][0];
            const float4 p1 = *(const float4*)&Xpart[b][jq + 1][0];
            const float4 p2 = *(const float4*)&Xpart[b][jq + 2][0];
            const float4 p3 = *(const float4*)&Xpart[b][jq + 3][0];
            r.x = tanh_fast(p0.x + p0.y + p0.z + p0.w + bias4[k].x);
            r.y = tanh_fast(p1.x + p1.y + p1.z + p1.w + bias4[k].y);
            r.z = tanh_fast(p2.x + p2.y + p2.z + p2.w + bias4[k].z);
            r.w = tanh_fast(p3.x + p3.y + p3.z + p3.w + bias4[k].w);
          }
          double* dst = layer ? ((double*)h1r + (size_t)cur * (SLOT / 2))
                              : ((double*)h0r + (size_t)wr0 * (SLOT / 2));
          const size_t di = (size_t)(bbase + b) * 256 + ((jbase + jq) >> 1);
          st2(&dst[di],     make_float2(r.x, r.y));
          st2(&dst[di + 1], make_float2(r.z, r.w));
          if (p == plast) {   // fused epilogue: own tile = own output
            if (layer == 0) {
              *(float4*)&out[32768 + (size_t)(bbase + b) * 1024 + jbase + jq] = r;
            } else {
              *(float4*)&out[(size_t)(bbase + b) * 512 + jbase + jq] = r;
              *(float4*)&out[32768 + (size_t)(bbase + b) * 1024 + 512 + jbase + jq] = r;
            }
          }
        }
      }
    }

    // ---- exchange: drain -> EARLY flag publish -> prefetch -> detect ----
    // Ring data is written and drained exclusively by wave 0, so the flag
    // publish needs only wave0's vmcnt(0) — not the barrier join.
    WAIT_VM0();
    if (tid == 0 && active)   // l0 publishes p+1 slots, l1 publishes p
      __hip_atomic_store(Fown, (u32)(layer ? p : (p + 1)),
                         __ATOMIC_RELAXED, __HIP_MEMORY_SCOPE_AGENT);
    __syncthreads();
    const int np = p + 1;
    if (layer == 0 && np <= plast) {
      #pragma unroll
      for (int i = 0; i < 2; ++i) {
        const int u = tid + NTHR * i;
        const int r = u >> 7, c = (u & 127) * 4;
        const int tok = x[(bbase + r) * SEQ + np];
        pf[i] = *(const float4*)&emb[(size_t)tok * HID + c];
      }
    }
    if (np <= P) {
      if (tid < 64) {
        u32* fp  = Fown;            // dummy for idle lanes (always valid)
        u32  tgt = 0;
        bool ok  = true;            // idle lanes start satisfied
        if (lane < NWG) { fp = F0 + lane * 32; tgt = (u32)np; ok = false; }
        else if (lane < 2 * NWG) {
          if (layer) {
            fp = F1 + (lane - NWG) * 32; tgt = (u32)(np - 1); ok = false;
          } else {
            const int th = np + 1 - ring;   // ring WAR throttle
            if (th > 0) { fp = F1 + (lane - NWG) * 32; tgt = (u32)th; ok = false; }
          }
        }
        // latched poll + backoff: max-of-8 straggler instead of max-of-16
        while (true) {
          if (!ok) ok = (ldf(fp) >= tgt);
          if (__ballot(ok) == ~0ull) break;
          __builtin_amdgcn_s_sleep(1);
        }
      }
      __syncthreads();
    }
    prev = cur; cur = wr0;
  }
}

extern "C" void kernel_launch(void* const* d_in, const int* in_sizes, int n_in,
                              void* d_out, int out_size, void* d_ws, size_t ws_size,
                              hipStream_t stream) {
  (void)in_sizes; (void)n_in; (void)out_size; (void)ws_size;
  const int*   x       = (const int*)d_in[0];
  const int*   lengths = (const int*)d_in[1];
  const float* emb     = (const float*)d_in[2];
  const float* W_ih    = (const float*)d_in[3];
  const float* W_hh    = (const float*)d_in[4];
  const float* b_ih    = (const float*)d_in[5];
  const float* b_hh    = (const float*)d_in[6];
  float* out = (float*)d_out;

  const size_t slotB = (size_t)SLOT * sizeof(float);   // 128KB
  const int ring = RING;                               // 8

  float* h0r = (float*)d_ws;
  float* h1r = h0r + (size_t)ring * SLOT;
  u32*   F   = (u32*)(h1r + (size_t)ring * SLOT);

  // zero slot 0 of each ring (h(-1)=0) + flag page; ws re-poisoned each call
  hipMemsetAsync(h0r, 0, slotB, stream);
  hipMemsetAsync(h1r, 0, slotB, stream);
  hipMemsetAsync(F, 0, 32768, stream);

  // grid: 8 doms x 2 layers x NWG(8) = 128 WGs of 512 threads
  hipLaunchKernelGGL(rnn_persistent, dim3(128), dim3(NTHR), 0, stream,
                     x, lengths, emb, W_ih, W_hh, b_ih, b_hh, out,
                     h0r, h1r, F, ring);
}